// Round 1
// baseline (326.461 us; speedup 1.0000x reference)
//
#include <hip/hip_runtime.h>
#include <hip/hip_bf16.h>

typedef __attribute__((ext_vector_type(8))) short bf16x8;
typedef __attribute__((ext_vector_type(4))) float f32x4;

constexpr int kB = 4, kC = 64, kH = 64, kW = 64;
constexpr int kHW = kH * kW;      // 4096
constexpr int kD  = kC * 9;       // 576 descriptor dim (c*9 + patch)
constexpr int kDP = kD + 8;       // 584: LDS pitch, 16B-aligned rows, 2-way banks on b128
constexpr int QBLK = 32, KBLK = 32;

// Features pre-scaled by sqrt(10 * log2(e)) so MFMA emits logits in exp2 space:
// corr_stored = 10*log2e*corr  ->  softmax row = 2^(s - max)
#define FSCALE 3.79828370f

// ---------------- Phase 1: unfold + bf16 convert + pre-scale ----------------
__global__ __launch_bounds__(256)
void nlwa_unfold(const float* __restrict__ feat, __hip_bfloat16* __restrict__ Kd) {
    int idx = blockIdx.x * 256 + threadIdx.x;
    if (idx >= kB * kHW * kD) return;
    int d = idx % kD;
    int v = (idx / kD) % kHW;
    int b = idx / (kD * kHW);
    int c = d / 9, dl = d % 9;
    int y = (v >> 6) + dl / 3 - 1;
    int x = (v & 63) + dl % 3 - 1;
    float val = 0.f;
    if ((unsigned)y < (unsigned)kH && (unsigned)x < (unsigned)kW)
        val = feat[((b * kC + c) * kH + y) * kW + x];
    Kd[idx] = __float2bfloat16(val * FSCALE);
}

// ---------------- Phase 2: flash attention, Q=K=Kd, V=rgb ----------------
__global__ __launch_bounds__(256, 2)
void nlwa_attn(const __hip_bfloat16* __restrict__ Kd,
               const float* __restrict__ rgb,
               float* __restrict__ out) {
    __shared__ unsigned short Qs[QBLK][kDP];
    __shared__ unsigned short Ks[KBLK][kDP];
    __shared__ float mrg[4][16][5];   // [wave][row][{m,l,O0,O1,O2}]

    // XCD-chunked swizzle: 512 wgs, 8 XCDs -> each XCD serves (half of) one batch,
    // so its K panel (4.7 MB bf16) ~fits the 4 MiB XCD L2.
    int orig = blockIdx.x;
    int wg = (orig & 7) * 64 + (orig >> 3);
    int b  = wg >> 7;
    int q0 = (wg & 127) * QBLK;

    int tid  = threadIdx.x;
    int lane = tid & 63;
    int wid  = tid >> 6;
    int rg = wid >> 1, cg = wid & 1;   // row-group / col-half of the 32x32 S tile
    int lr = lane & 15, lg = lane >> 4;

    // stage Q tile once (rows q0..q0+31), uint4 = 8 bf16 per copy
    {
        const uint4* src = (const uint4*)(Kd + (size_t)(b * kHW + q0) * kD);
        #pragma unroll
        for (int it = 0; it < 9; ++it) {
            int f = it * 256 + tid;          // 0..2303, 72 uint4 per row
            int r = f / 72, ch = f % 72;
            *(uint4*)&Qs[r][ch * 8] = src[r * 72 + ch];
        }
    }

    float m[4], l[4], O[4][3];
    #pragma unroll
    for (int r = 0; r < 4; ++r) {
        m[r] = -INFINITY; l[r] = 0.f;
        O[r][0] = O[r][1] = O[r][2] = 0.f;
    }

    for (int kt = 0; kt < kHW / KBLK; ++kt) {
        int kv0 = kt * KBLK;
        __syncthreads();
        {
            const uint4* src = (const uint4*)(Kd + (size_t)(b * kHW + kv0) * kD);
            #pragma unroll
            for (int it = 0; it < 9; ++it) {
                int f = it * 256 + tid;
                int r = f / 72, ch = f % 72;
                *(uint4*)&Ks[r][ch * 8] = src[r * 72 + ch];
            }
        }
        __syncthreads();

        f32x4 acc = {0.f, 0.f, 0.f, 0.f};
        #pragma unroll
        for (int dc = 0; dc < 18; ++dc) {
            bf16x8 a = *(const bf16x8*)&Qs[rg * 16 + lr][dc * 32 + lg * 8];
            bf16x8 k = *(const bf16x8*)&Ks[cg * 16 + lr][dc * 32 + lg * 8];
            acc = __builtin_amdgcn_mfma_f32_16x16x32_bf16(a, k, acc, 0, 0, 0);
        }
        // lane holds S[row=(lg*4+r)][col=lr] (verified m89/m91 C/D layout)

        int kv = kv0 + cg * 16 + lr;
        float r0 = rgb[(b * 3 + 0) * kHW + kv];
        float r1 = rgb[(b * 3 + 1) * kHW + kv];
        float r2 = rgb[(b * 3 + 2) * kHW + kv];
        #pragma unroll
        for (int r = 0; r < 4; ++r) {
            float s = acc[r];
            float v = s;                                  // row max over 16 col lanes
            #pragma unroll
            for (int off = 1; off < 16; off <<= 1)
                v = fmaxf(v, __shfl_xor(v, off));
            float mn = fmaxf(m[r], v);
            float al = exp2f(m[r] - mn);                  // -inf start -> 0
            float p  = exp2f(s - mn);
            float ps = p;                                 // row sum
            #pragma unroll
            for (int off = 1; off < 16; off <<= 1)
                ps += __shfl_xor(ps, off);
            m[r] = mn;
            l[r] = l[r] * al + ps;
            O[r][0] = O[r][0] * al + p * r0;
            O[r][1] = O[r][1] * al + p * r1;
            O[r][2] = O[r][2] * al + p * r2;
        }
    }

    // reduce per-lane O partials across the 16 column lanes
    #pragma unroll
    for (int r = 0; r < 4; ++r)
        #pragma unroll
        for (int c = 0; c < 3; ++c) {
            float v = O[r][c];
            #pragma unroll
            for (int off = 1; off < 16; off <<= 1)
                v += __shfl_xor(v, off);
            O[r][c] = v;
        }

    if (lr == 0) {
        #pragma unroll
        for (int r = 0; r < 4; ++r) {
            int row = lg * 4 + r;
            mrg[wid][row][0] = m[r];
            mrg[wid][row][1] = l[r];
            mrg[wid][row][2] = O[r][0];
            mrg[wid][row][3] = O[r][1];
            mrg[wid][row][4] = O[r][2];
        }
    }
    __syncthreads();

    // merge the two col-halves (waves w, w+1), write output
    if ((wid & 1) == 0 && lane < 16) {
        int row = lane;
        float m0 = mrg[wid][row][0],     l0 = mrg[wid][row][1];
        float m1 = mrg[wid + 1][row][0], l1 = mrg[wid + 1][row][1];
        float mt = fmaxf(m0, m1);
        float a0 = exp2f(m0 - mt), a1 = exp2f(m1 - mt);
        float inv = 1.f / (l0 * a0 + l1 * a1);
        int q = q0 + rg * 16 + row;
        #pragma unroll
        for (int c = 0; c < 3; ++c) {
            float o = mrg[wid][row][2 + c] * a0 + mrg[wid + 1][row][2 + c] * a1;
            out[(b * 3 + c) * kHW + q] = o * inv;
        }
    }
}

// ---------------- Fallback (only if ws too small): slow fp32, correct ----------------
__global__ __launch_bounds__(64)
void nlwa_naive(const float* __restrict__ feat, const float* __restrict__ rgb,
                float* __restrict__ out) {
    int p = blockIdx.x, b = blockIdx.y;
    int pi = p >> 6, pj = p & 63;
    int t = threadIdx.x;
    __shared__ float pdesc[kD];
    __shared__ float rows[kC][3][kW];
    __shared__ float red[64][5];

    for (int d = t; d < kD; d += 64) {
        int c = d / 9, dl = d % 9;
        int y = pi + dl / 3 - 1, x = pj + dl % 3 - 1;
        pdesc[d] = ((unsigned)y < 64u && (unsigned)x < 64u)
                 ? feat[((b * kC + c) * kH + y) * kW + x] : 0.f;
    }
    float m = -INFINITY, l = 0.f, O0 = 0.f, O1 = 0.f, O2 = 0.f;
    for (int qi = 0; qi < kH; ++qi) {
        __syncthreads();
        for (int f = t; f < kC * 3 * kW; f += 64) {
            int x = f & 63, yy = (f >> 6) % 3, c = f / (3 * kW);
            int y = qi + yy - 1;
            rows[c][yy][x] = ((unsigned)y < 64u) ? feat[((b * kC + c) * kH + y) * kW + x] : 0.f;
        }
        __syncthreads();
        float s = 0.f;
        for (int c = 0; c < kC; ++c)
            for (int dl = 0; dl < 9; ++dl) {
                int x = t + dl % 3 - 1;
                float fv = ((unsigned)x < 64u) ? rows[c][dl / 3][x] : 0.f;
                s += pdesc[c * 9 + dl] * fv;
            }
        s *= 14.4269504089f;   // 10*log2e
        int q = qi * 64 + t;
        float mn = fmaxf(m, s);
        float al = exp2f(m - mn);
        float pv = exp2f(s - mn);
        l = l * al + pv;
        O0 = O0 * al + pv * rgb[(b * 3 + 0) * kHW + q];
        O1 = O1 * al + pv * rgb[(b * 3 + 1) * kHW + q];
        O2 = O2 * al + pv * rgb[(b * 3 + 2) * kHW + q];
        m = mn;
    }
    red[t][0] = m; red[t][1] = l; red[t][2] = O0; red[t][3] = O1; red[t][4] = O2;
    __syncthreads();
    if (t == 0) {
        float M = -INFINITY;
        for (int i = 0; i < 64; ++i) M = fmaxf(M, red[i][0]);
        float L = 0, A = 0, Bv = 0, Cv = 0;
        for (int i = 0; i < 64; ++i) {
            float a = exp2f(red[i][0] - M);
            L += red[i][1] * a; A += red[i][2] * a; Bv += red[i][3] * a; Cv += red[i][4] * a;
        }
        out[(b * 3 + 0) * kHW + p] = A / L;
        out[(b * 3 + 1) * kHW + p] = Bv / L;
        out[(b * 3 + 2) * kHW + p] = Cv / L;
    }
}

extern "C" void kernel_launch(void* const* d_in, const int* in_sizes, int n_in,
                              void* d_out, int out_size, void* d_ws, size_t ws_size,
                              hipStream_t stream) {
    const float* x_rgb   = (const float*)d_in[0];   // [4,3,64,64]
    const float* feature = (const float*)d_in[1];   // [4,64,64,64]
    float* out = (float*)d_out;                     // [4,3,64,64]

    size_t need = (size_t)kB * kHW * kD * sizeof(__hip_bfloat16);  // 18.9 MB
    if (ws_size >= need) {
        __hip_bfloat16* Kd = (__hip_bfloat16*)d_ws;
        int total = kB * kHW * kD;
        nlwa_unfold<<<dim3((total + 255) / 256), 256, 0, stream>>>(feature, Kd);
        nlwa_attn<<<dim3(kB * (kHW / QBLK)), 256, 0, stream>>>(Kd, x_rgb, out);
    } else {
        nlwa_naive<<<dim3(kHW, kB), 64, 0, stream>>>(feature, x_rgb, out);
    }
}

// Round 2
// 150.633 us; speedup vs baseline: 2.1673x; 2.1673x over previous
//
#include <hip/hip_runtime.h>
#include <hip/hip_bf16.h>

typedef __attribute__((ext_vector_type(8))) short bf16x8;
typedef __attribute__((ext_vector_type(4))) float f32x4;

constexpr int kB = 4, kC = 64, kH = 64, kW = 64;
constexpr int kHW = kH * kW;      // 4096
constexpr int kD  = kC * 9;       // 576
constexpr int KSPLIT = 4;
constexpr int KBLK = 32;
constexpr int QWAVE = 32;         // q rows per wave (2 groups of 16)
constexpr int QWG = 128;          // 4 waves
constexpr int NTILE = kHW / KSPLIT / KBLK;   // 32

// Features pre-scaled by sqrt(10*log2e): S = mfma(K,Q) is directly in exp2 space.
#define FSCALE 3.79828370f

// ---------------- Phase 1: unfold + bf16 + pre-scale + T2 XOR pre-swizzle ----------------
// Element (b,v,d) stored at chunk (d>>3) ^ (v&7) within its row (16B chunks, 72/row).
__global__ __launch_bounds__(256)
void nlwa_unfold(const float* __restrict__ feat, unsigned short* __restrict__ Kd) {
    int idx = blockIdx.x * 256 + threadIdx.x;
    if (idx >= kB * kHW * kD) return;
    int d = idx % kD;
    int v = (idx / kD) % kHW;
    int b = idx / (kD * kHW);
    int c = d / 9, dl = d % 9;
    int y = (v >> 6) + dl / 3 - 1;
    int x = (v & 63) + dl % 3 - 1;
    float val = 0.f;
    if ((unsigned)y < 64u && (unsigned)x < 64u)
        val = feat[((b * kC + c) * kH + y) * kW + x] * FSCALE;
    int chunk = (d >> 3) ^ (v & 7);
    __hip_bfloat16 h = __float2bfloat16(val);
    Kd[(size_t)(b * kHW + v) * kD + (chunk << 3) + (d & 7)] = *(unsigned short*)&h;
}

// ---------------- Phase 2: flash attention, swapped mfma(K,Q), Q in regs ----------------
__global__ __launch_bounds__(256, 2)
void nlwa_attn(const unsigned short* __restrict__ Kd,
               const float* __restrict__ rgb,
               float* __restrict__ part) {
    __shared__ alignas(16) unsigned short Ks[2][KBLK][kD];   // 73,728 B

    // XCD-chunked swizzle: 512 wgs, consecutive 64 per XCD share 2 (b,ks) K panels (~2.4MB -> L2).
    int orig = blockIdx.x;
    int wg = (orig & 7) * 64 + (orig >> 3);
    int qblk = wg & 31;
    int pair = wg >> 5;
    int ks = pair & 3;
    int b  = pair >> 2;

    int tid = threadIdx.x, lane = tid & 63, wid = tid >> 6;
    int lr = lane & 15, lg = lane >> 4;
    int qwave = qblk * QWG + wid * QWAVE;
    int k0 = ks * (kHW / KSPLIT);

    // ---- Q fragments to registers: 2 groups x 18 d-chunks (B-operand layout) ----
    bf16x8 qf[2][18];
    #pragma unroll
    for (int g = 0; g < 2; ++g) {
        int qrow = qwave + g * 16 + lr;
        const unsigned short* qbase = Kd + (size_t)(b * kHW + qrow) * kD;
        int s7 = qrow & 7;
        #pragma unroll
        for (int dc = 0; dc < 18; ++dc) {
            int chunk = (dc * 4 + lg) ^ s7;
            qf[g][dc] = *(const bf16x8*)(qbase + (chunk << 3));
        }
    }

    float m[2] = {-INFINITY, -INFINITY};
    float l[2] = {0.f, 0.f};
    float O[2][3] = {{0.f,0.f,0.f},{0.f,0.f,0.f}};

    const unsigned short* ksrc = Kd + (size_t)(b * kHW + k0) * kD;
    unsigned short* lds0 = &Ks[0][0][0];

    auto stage = [&](int t, int buf) {
        const unsigned short* src = ksrc + (size_t)t * KBLK * kD;
        unsigned short* dstb = lds0 + (size_t)buf * KBLK * kD;
        #pragma unroll
        for (int it = 0; it < 9; ++it) {
            int base = it * 256 + wid * 64;   // wave-uniform chunk base
            __builtin_amdgcn_global_load_lds(
                (const __attribute__((address_space(1))) void*)(src + (size_t)(base + lane) * 8),
                (__attribute__((address_space(3))) void*)(dstb + (size_t)base * 8),
                16, 0, 0);
        }
    };

    stage(0, 0);
    __syncthreads();   // drains vmcnt(0): tile 0 resident

    int buf = 0;
    for (int t = 0; t < NTILE; ++t) {
        if (t + 1 < NTILE) stage(t + 1, buf ^ 1);   // prefetch next, other buffer

        const unsigned short* kb = lds0 + (size_t)buf * KBLK * kD;
        f32x4 acc[2][2];
        #pragma unroll
        for (int g = 0; g < 2; ++g)
            #pragma unroll
            for (int s = 0; s < 2; ++s)
                acc[g][s] = (f32x4){0.f, 0.f, 0.f, 0.f};

        #pragma unroll
        for (int dc = 0; dc < 18; ++dc) {
            #pragma unroll
            for (int s = 0; s < 2; ++s) {
                int rr = s * 16 + lr;
                int chunk = (dc * 4 + lg) ^ (lr & 7);     // rr&7 == lr&7
                bf16x8 a = *(const bf16x8*)(kb + rr * kD + (chunk << 3));
                acc[0][s] = __builtin_amdgcn_mfma_f32_16x16x32_bf16(a, qf[0][dc], acc[0][s], 0, 0, 0);
                acc[1][s] = __builtin_amdgcn_mfma_f32_16x16x32_bf16(a, qf[1][dc], acc[1][s], 0, 0, 0);
            }
        }
        // acc[g][s][r] = S[k = k0 + t*32 + s*16 + lg*4 + r][q = qwave + g*16 + lr]

        float pm[2];
        #pragma unroll
        for (int g = 0; g < 2; ++g)
            pm[g] = fmaxf(
                fmaxf(fmaxf(acc[g][0][0], acc[g][0][1]), fmaxf(acc[g][0][2], acc[g][0][3])),
                fmaxf(fmaxf(acc[g][1][0], acc[g][1][1]), fmaxf(acc[g][1][2], acc[g][1][3])));

        float dmx = fmaxf(pm[0] - m[0], pm[1] - m[1]);
        #pragma unroll
        for (int off = 1; off < 64; off <<= 1)
            dmx = fmaxf(dmx, __shfl_xor(dmx, off));

        if (dmx >= -25.f) {   // wave-uniform: tile contributes
            int kt0 = k0 + t * KBLK;
            #pragma unroll
            for (int g = 0; g < 2; ++g) {
                float v = pm[g];
                v = fmaxf(v, __shfl_xor(v, 16));
                v = fmaxf(v, __shfl_xor(v, 32));          // per-q tile max (uniform over lg)
                float mn = fmaxf(m[g], v);
                float al = exp2f(m[g] - mn);
                m[g] = mn;
                l[g] *= al;
                O[g][0] *= al; O[g][1] *= al; O[g][2] *= al;
            }
            float4 rv[2][3];
            #pragma unroll
            for (int s = 0; s < 2; ++s)
                #pragma unroll
                for (int c = 0; c < 3; ++c)
                    rv[s][c] = *(const float4*)(rgb + (size_t)(b * 3 + c) * kHW + kt0 + s * 16 + lg * 4);
            #pragma unroll
            for (int g = 0; g < 2; ++g) {
                #pragma unroll
                for (int s = 0; s < 2; ++s) {
                    float p0 = exp2f(acc[g][s][0] - m[g]);
                    float p1 = exp2f(acc[g][s][1] - m[g]);
                    float p2 = exp2f(acc[g][s][2] - m[g]);
                    float p3 = exp2f(acc[g][s][3] - m[g]);
                    l[g] += p0 + p1 + p2 + p3;
                    #pragma unroll
                    for (int c = 0; c < 3; ++c)
                        O[g][c] += p0 * rv[s][c].x + p1 * rv[s][c].y
                                 + p2 * rv[s][c].z + p3 * rv[s][c].w;
                }
            }
        }
        __syncthreads();   // staged next-tile landed; all waves done reading buf
        buf ^= 1;
    }

    // final cross-group (lg) reduction of per-lane partials
    #pragma unroll
    for (int g = 0; g < 2; ++g) {
        l[g] += __shfl_xor(l[g], 16); l[g] += __shfl_xor(l[g], 32);
        #pragma unroll
        for (int c = 0; c < 3; ++c) {
            O[g][c] += __shfl_xor(O[g][c], 16);
            O[g][c] += __shfl_xor(O[g][c], 32);
        }
    }
    if (lg == 0) {
        #pragma unroll
        for (int g = 0; g < 2; ++g) {
            int q = qwave + g * 16 + lr;
            float* p = part + ((size_t)(b * kHW + q) * KSPLIT + ks) * 5;
            p[0] = m[g]; p[1] = l[g]; p[2] = O[g][0]; p[3] = O[g][1]; p[4] = O[g][2];
        }
    }
}

// ---------------- Phase 3: merge the KSPLIT partials ----------------
__global__ __launch_bounds__(256)
void nlwa_merge(const float* __restrict__ part, float* __restrict__ out) {
    int idx = blockIdx.x * 256 + threadIdx.x;
    if (idx >= kB * kHW) return;
    int b = idx >> 12, q = idx & 4095;
    const float* p = part + (size_t)idx * KSPLIT * 5;
    float M = -INFINITY;
    #pragma unroll
    for (int s = 0; s < KSPLIT; ++s) M = fmaxf(M, p[s * 5]);
    float L = 0.f, o0 = 0.f, o1 = 0.f, o2 = 0.f;
    #pragma unroll
    for (int s = 0; s < KSPLIT; ++s) {
        float a = exp2f(p[s * 5] - M);
        L  += p[s * 5 + 1] * a;
        o0 += p[s * 5 + 2] * a;
        o1 += p[s * 5 + 3] * a;
        o2 += p[s * 5 + 4] * a;
    }
    float inv = 1.f / L;
    out[(b * 3 + 0) * kHW + q] = o0 * inv;
    out[(b * 3 + 1) * kHW + q] = o1 * inv;
    out[(b * 3 + 2) * kHW + q] = o2 * inv;
}

// ---------------- Fallback (ws too small): slow fp32, correct ----------------
__global__ __launch_bounds__(64)
void nlwa_naive(const float* __restrict__ feat, const float* __restrict__ rgb,
                float* __restrict__ out) {
    int p = blockIdx.x, b = blockIdx.y;
    int pi = p >> 6, pj = p & 63;
    int t = threadIdx.x;
    __shared__ float pdesc[kD];
    __shared__ float rows[kC][3][kW];
    __shared__ float red[64][5];

    for (int d = t; d < kD; d += 64) {
        int c = d / 9, dl = d % 9;
        int y = pi + dl / 3 - 1, x = pj + dl % 3 - 1;
        pdesc[d] = ((unsigned)y < 64u && (unsigned)x < 64u)
                 ? feat[((b * kC + c) * kH + y) * kW + x] : 0.f;
    }
    float m = -INFINITY, l = 0.f, O0 = 0.f, O1 = 0.f, O2 = 0.f;
    for (int qi = 0; qi < kH; ++qi) {
        __syncthreads();
        for (int f = t; f < kC * 3 * kW; f += 64) {
            int x = f & 63, yy = (f >> 6) % 3, c = f / (3 * kW);
            int y = qi + yy - 1;
            rows[c][yy][x] = ((unsigned)y < 64u) ? feat[((b * kC + c) * kH + y) * kW + x] : 0.f;
        }
        __syncthreads();
        float s = 0.f;
        for (int c = 0; c < kC; ++c)
            for (int dl = 0; dl < 9; ++dl) {
                int x = t + dl % 3 - 1;
                float fv = ((unsigned)x < 64u) ? rows[c][dl / 3][x] : 0.f;
                s += pdesc[c * 9 + dl] * fv;
            }
        s *= 14.4269504089f;
        int q = qi * 64 + t;
        float mn = fmaxf(m, s);
        float al = exp2f(m - mn);
        float pv = exp2f(s - mn);
        l = l * al + pv;
        O0 = O0 * al + pv * rgb[(b * 3 + 0) * kHW + q];
        O1 = O1 * al + pv * rgb[(b * 3 + 1) * kHW + q];
        O2 = O2 * al + pv * rgb[(b * 3 + 2) * kHW + q];
        m = mn;
    }
    red[t][0] = m; red[t][1] = l; red[t][2] = O0; red[t][3] = O1; red[t][4] = O2;
    __syncthreads();
    if (t == 0) {
        float M = -INFINITY;
        for (int i = 0; i < 64; ++i) M = fmaxf(M, red[i][0]);
        float L = 0, A = 0, Bv = 0, Cv = 0;
        for (int i = 0; i < 64; ++i) {
            float a = exp2f(red[i][0] - M);
            L += red[i][1] * a; A += red[i][2] * a; Bv += red[i][3] * a; Cv += red[i][4] * a;
        }
        out[(b * 3 + 0) * kHW + p] = A / L;
        out[(b * 3 + 1) * kHW + p] = Bv / L;
        out[(b * 3 + 2) * kHW + p] = Cv / L;
    }
}

extern "C" void kernel_launch(void* const* d_in, const int* in_sizes, int n_in,
                              void* d_out, int out_size, void* d_ws, size_t ws_size,
                              hipStream_t stream) {
    const float* x_rgb   = (const float*)d_in[0];   // [4,3,64,64]
    const float* feature = (const float*)d_in[1];   // [4,64,64,64]
    float* out = (float*)d_out;                     // [4,3,64,64]

    size_t needK = (size_t)kB * kHW * kD * 2;              // 18.87 MB
    size_t needP = (size_t)kB * kHW * KSPLIT * 5 * 4;      // 1.31 MB
    if (ws_size >= needK + needP) {
        unsigned short* Kd = (unsigned short*)d_ws;
        float* partb = (float*)((char*)d_ws + needK);
        int total = kB * kHW * kD;
        nlwa_unfold<<<(total + 255) / 256, 256, 0, stream>>>(feature, Kd);
        nlwa_attn<<<kB * 32 * KSPLIT, 256, 0, stream>>>(Kd, x_rgb, partb);
        nlwa_merge<<<(kB * kHW + 255) / 256, 256, 0, stream>>>(partb, out);
    } else {
        nlwa_naive<<<dim3(kHW, kB), 64, 0, stream>>>(feature, x_rgb, out);
    }
}

// Round 3
// 124.863 us; speedup vs baseline: 2.6146x; 1.2064x over previous
//
#include <hip/hip_runtime.h>
#include <hip/hip_bf16.h>

typedef __attribute__((ext_vector_type(8))) short bf16x8;
typedef __attribute__((ext_vector_type(4))) float f32x4;

constexpr int kB = 4, kC = 64, kH = 64, kW = 64;
constexpr int kHW = kH * kW;      // 4096
constexpr int kD  = kC * 9;       // 576
constexpr int KSPLIT = 4;
constexpr int KBLK = 32;
constexpr int QWAVE = 64;         // q rows per wave (4 groups of 16)
constexpr int QWG = 256;          // 4 waves * 64 q
constexpr int NTILE = kHW / KSPLIT / KBLK;   // 32

// Features pre-scaled by sqrt(10*log2e): S = mfma(K,Q) is directly in exp2 space.
#define FSCALE 3.79828370f

__device__ inline float bf16bits_to_f32(unsigned short u) {
    unsigned int w = ((unsigned int)u) << 16;
    return __builtin_bit_cast(float, w);
}

// ---------------- Phase 1: unfold + bf16 + pre-scale + T2 XOR pre-swizzle ----------------
// Element (b,v,d) stored at chunk (d>>3) ^ (v&7) within its row (16B chunks, 72/row).
__global__ __launch_bounds__(256)
void nlwa_unfold(const float* __restrict__ feat, unsigned short* __restrict__ Kd) {
    int idx = blockIdx.x * 256 + threadIdx.x;
    if (idx >= kB * kHW * kD) return;
    int d = idx % kD;
    int v = (idx / kD) % kHW;
    int b = idx / (kD * kHW);
    int c = d / 9, dl = d % 9;
    int y = (v >> 6) + dl / 3 - 1;
    int x = (v & 63) + dl % 3 - 1;
    float val = 0.f;
    if ((unsigned)y < 64u && (unsigned)x < 64u)
        val = feat[((b * kC + c) * kH + y) * kW + x] * FSCALE;
    int chunk = (d >> 3) ^ (v & 7);
    __hip_bfloat16 h = __float2bfloat16(val);
    Kd[(size_t)(b * kHW + v) * kD + (chunk << 3) + (d & 7)] = *(unsigned short*)&h;
}

// ---------------- Phase 2: flash attention, swapped mfma(K,Q), 64 q rows per wave ----------------
__global__ __launch_bounds__(256, 1)
void nlwa_attn(const unsigned short* __restrict__ Kd,
               const float* __restrict__ rgb,
               float* __restrict__ part) {
    __shared__ alignas(16) unsigned short Ks[2][KBLK][kD];   // 73,728 B

    // XCD-chunked swizzle: 256 wgs, 32 consecutive per XCD -> 2 (b,ks) K panels (~2.4MB) in its L2.
    int orig = blockIdx.x;
    int wg = (orig & 7) * 32 + (orig >> 3);
    int qblk = wg & 15;
    int pair = wg >> 4;
    int ks = pair & 3;
    int b  = pair >> 2;

    int tid = threadIdx.x, lane = tid & 63, wid = tid >> 6;
    int lr = lane & 15, lg = lane >> 4;
    int qwave = qblk * QWG + wid * QWAVE;
    int k0 = ks * (kHW / KSPLIT);

    // ---- Q fragments to registers: 4 groups x 18 d-chunks (B-operand layout) ----
    bf16x8 qf[4][18];
    #pragma unroll
    for (int g = 0; g < 4; ++g) {
        int qrow = qwave + g * 16 + lr;
        const unsigned short* qbase = Kd + (size_t)(b * kHW + qrow) * kD;
        int s7 = qrow & 7;
        #pragma unroll
        for (int dc = 0; dc < 18; ++dc) {
            int chunk = (dc * 4 + lg) ^ s7;
            qf[g][dc] = *(const bf16x8*)(qbase + (chunk << 3));
        }
    }

    // ---- Seed online-softmax max with the self-logit  m = sum_d q_d^2 ----
    // (exact for any seed; self-logit is this q's diagonal S value up to rounding)
    float m[4], l[4] = {0.f, 0.f, 0.f, 0.f};
    float O[4][3] = {{0,0,0},{0,0,0},{0,0,0},{0,0,0}};
    #pragma unroll
    for (int g = 0; g < 4; ++g) {
        float ss = 0.f;
        #pragma unroll
        for (int dc = 0; dc < 18; ++dc)
            #pragma unroll
            for (int j = 0; j < 8; ++j) {
                float v = bf16bits_to_f32((unsigned short)qf[g][dc][j]);
                ss = fmaf(v, v, ss);
            }
        ss += __shfl_xor(ss, 16);
        ss += __shfl_xor(ss, 32);   // row self-logit (sum over all 4 lg quarters)
        m[g] = ss;
    }

    const unsigned short* ksrc = Kd + (size_t)(b * kHW + k0) * kD;
    unsigned short* lds0 = &Ks[0][0][0];

    auto stage = [&](int t, int buf) {
        const unsigned short* src = ksrc + (size_t)t * KBLK * kD;
        unsigned short* dstb = lds0 + (size_t)buf * KBLK * kD;
        #pragma unroll
        for (int it = 0; it < 9; ++it) {
            int base = it * 256 + wid * 64;   // wave-uniform chunk base
            __builtin_amdgcn_global_load_lds(
                (const __attribute__((address_space(1))) void*)(src + (size_t)(base + lane) * 8),
                (__attribute__((address_space(3))) void*)(dstb + (size_t)base * 8),
                16, 0, 0);
        }
    };

    stage(0, 0);
    __syncthreads();   // tile 0 resident

    int buf = 0;
    for (int t = 0; t < NTILE; ++t) {
        if (t + 1 < NTILE) stage(t + 1, buf ^ 1);   // prefetch next into other buffer

        const unsigned short* kb = lds0 + (size_t)buf * KBLK * kD;
        f32x4 acc[4][2];
        #pragma unroll
        for (int g = 0; g < 4; ++g)
            #pragma unroll
            for (int s = 0; s < 2; ++s)
                acc[g][s] = (f32x4){0.f, 0.f, 0.f, 0.f};

        #pragma unroll
        for (int dc = 0; dc < 18; ++dc) {
            #pragma unroll
            for (int s = 0; s < 2; ++s) {
                int rr = s * 16 + lr;
                int chunk = (dc * 4 + lg) ^ (lr & 7);     // rr&7 == lr&7
                bf16x8 a = *(const bf16x8*)(kb + rr * kD + (chunk << 3));
                acc[0][s] = __builtin_amdgcn_mfma_f32_16x16x32_bf16(a, qf[0][dc], acc[0][s], 0, 0, 0);
                acc[1][s] = __builtin_amdgcn_mfma_f32_16x16x32_bf16(a, qf[1][dc], acc[1][s], 0, 0, 0);
                acc[2][s] = __builtin_amdgcn_mfma_f32_16x16x32_bf16(a, qf[2][dc], acc[2][s], 0, 0, 0);
                acc[3][s] = __builtin_amdgcn_mfma_f32_16x16x32_bf16(a, qf[3][dc], acc[3][s], 0, 0, 0);
            }
        }
        // acc[g][s][r] = S[k = k0 + t*32 + s*16 + lg*4 + r][q = qwave + g*16 + lr]

        float pm[4];
        #pragma unroll
        for (int g = 0; g < 4; ++g)
            pm[g] = fmaxf(
                fmaxf(fmaxf(acc[g][0][0], acc[g][0][1]), fmaxf(acc[g][0][2], acc[g][0][3])),
                fmaxf(fmaxf(acc[g][1][0], acc[g][1][1]), fmaxf(acc[g][1][2], acc[g][1][3])));

        float dmx = fmaxf(fmaxf(pm[0] - m[0], pm[1] - m[1]),
                          fmaxf(pm[2] - m[2], pm[3] - m[3]));
        if (__any(dmx >= -25.f)) {   // cheap wave-uniform liveness test
            int kt0 = k0 + t * KBLK;
            #pragma unroll
            for (int g = 0; g < 4; ++g) {
                float v = pm[g];
                v = fmaxf(v, __shfl_xor(v, 16));
                v = fmaxf(v, __shfl_xor(v, 32));          // per-q tile max (uniform over lg)
                float mn = fmaxf(m[g], v);
                float al = exp2f(m[g] - mn);
                m[g] = mn;
                l[g] *= al;
                O[g][0] *= al; O[g][1] *= al; O[g][2] *= al;
            }
            float4 rv[2][3];
            #pragma unroll
            for (int s = 0; s < 2; ++s)
                #pragma unroll
                for (int c = 0; c < 3; ++c)
                    rv[s][c] = *(const float4*)(rgb + (size_t)(b * 3 + c) * kHW + kt0 + s * 16 + lg * 4);
            #pragma unroll
            for (int g = 0; g < 4; ++g) {
                #pragma unroll
                for (int s = 0; s < 2; ++s) {
                    float p0 = exp2f(acc[g][s][0] - m[g]);
                    float p1 = exp2f(acc[g][s][1] - m[g]);
                    float p2 = exp2f(acc[g][s][2] - m[g]);
                    float p3 = exp2f(acc[g][s][3] - m[g]);
                    l[g] += p0 + p1 + p2 + p3;
                    #pragma unroll
                    for (int c = 0; c < 3; ++c)
                        O[g][c] += p0 * rv[s][c].x + p1 * rv[s][c].y
                                 + p2 * rv[s][c].z + p3 * rv[s][c].w;
                }
            }
        }
        __syncthreads();   // prefetch landed; all waves done with buf
        buf ^= 1;
    }

    // final cross-group (lg) reduction of per-lane partials
    #pragma unroll
    for (int g = 0; g < 4; ++g) {
        l[g] += __shfl_xor(l[g], 16); l[g] += __shfl_xor(l[g], 32);
        #pragma unroll
        for (int c = 0; c < 3; ++c) {
            O[g][c] += __shfl_xor(O[g][c], 16);
            O[g][c] += __shfl_xor(O[g][c], 32);
        }
    }
    if (lg == 0) {
        #pragma unroll
        for (int g = 0; g < 4; ++g) {
            int q = qwave + g * 16 + lr;
            float* p = part + ((size_t)(b * kHW + q) * KSPLIT + ks) * 5;
            p[0] = m[g]; p[1] = l[g]; p[2] = O[g][0]; p[3] = O[g][1]; p[4] = O[g][2];
        }
    }
}

// ---------------- Phase 3: merge the KSPLIT partials ----------------
__global__ __launch_bounds__(256)
void nlwa_merge(const float* __restrict__ part, float* __restrict__ out) {
    int idx = blockIdx.x * 256 + threadIdx.x;
    if (idx >= kB * kHW) return;
    int b = idx >> 12, q = idx & 4095;
    const float* p = part + (size_t)idx * KSPLIT * 5;
    float M = -INFINITY;
    #pragma unroll
    for (int s = 0; s < KSPLIT; ++s) M = fmaxf(M, p[s * 5]);
    float L = 0.f, o0 = 0.f, o1 = 0.f, o2 = 0.f;
    #pragma unroll
    for (int s = 0; s < KSPLIT; ++s) {
        float a = exp2f(p[s * 5] - M);
        L  += p[s * 5 + 1] * a;
        o0 += p[s * 5 + 2] * a;
        o1 += p[s * 5 + 3] * a;
        o2 += p[s * 5 + 4] * a;
    }
    float inv = 1.f / L;
    out[(b * 3 + 0) * kHW + q] = o0 * inv;
    out[(b * 3 + 1) * kHW + q] = o1 * inv;
    out[(b * 3 + 2) * kHW + q] = o2 * inv;
}

// ---------------- Fallback (ws too small): slow fp32, correct ----------------
__global__ __launch_bounds__(64)
void nlwa_naive(const float* __restrict__ feat, const float* __restrict__ rgb,
                float* __restrict__ out) {
    int p = blockIdx.x, b = blockIdx.y;
    int pi = p >> 6, pj = p & 63;
    int t = threadIdx.x;
    __shared__ float pdesc[kD];
    __shared__ float rows[kC][3][kW];
    __shared__ float red[64][5];

    for (int d = t; d < kD; d += 64) {
        int c = d / 9, dl = d % 9;
        int y = pi + dl / 3 - 1, x = pj + dl % 3 - 1;
        pdesc[d] = ((unsigned)y < 64u && (unsigned)x < 64u)
                 ? feat[((b * kC + c) * kH + y) * kW + x] : 0.f;
    }
    float m = -INFINITY, l = 0.f, O0 = 0.f, O1 = 0.f, O2 = 0.f;
    for (int qi = 0; qi < kH; ++qi) {
        __syncthreads();
        for (int f = t; f < kC * 3 * kW; f += 64) {
            int x = f & 63, yy = (f >> 6) % 3, c = f / (3 * kW);
            int y = qi + yy - 1;
            rows[c][yy][x] = ((unsigned)y < 64u) ? feat[((b * kC + c) * kH + y) * kW + x] : 0.f;
        }
        __syncthreads();
        float s = 0.f;
        for (int c = 0; c < kC; ++c)
            for (int dl = 0; dl < 9; ++dl) {
                int x = t + dl % 3 - 1;
                float fv = ((unsigned)x < 64u) ? rows[c][dl / 3][x] : 0.f;
                s += pdesc[c * 9 + dl] * fv;
            }
        s *= 14.4269504089f;
        int q = qi * 64 + t;
        float mn = fmaxf(m, s);
        float al = exp2f(m - mn);
        float pv = exp2f(s - mn);
        l = l * al + pv;
        O0 = O0 * al + pv * rgb[(b * 3 + 0) * kHW + q];
        O1 = O1 * al + pv * rgb[(b * 3 + 1) * kHW + q];
        O2 = O2 * al + pv * rgb[(b * 3 + 2) * kHW + q];
        m = mn;
    }
    red[t][0] = m; red[t][1] = l; red[t][2] = O0; red[t][3] = O1; red[t][4] = O2;
    __syncthreads();
    if (t == 0) {
        float M = -INFINITY;
        for (int i = 0; i < 64; ++i) M = fmaxf(M, red[i][0]);
        float L = 0, A = 0, Bv = 0, Cv = 0;
        for (int i = 0; i < 64; ++i) {
            float a = exp2f(red[i][0] - M);
            L += red[i][1] * a; A += red[i][2] * a; Bv += red[i][3] * a; Cv += red[i][4] * a;
        }
        out[(b * 3 + 0) * kHW + p] = A / L;
        out[(b * 3 + 1) * kHW + p] = Bv / L;
        out[(b * 3 + 2) * kHW + p] = Cv / L;
    }
}

extern "C" void kernel_launch(void* const* d_in, const int* in_sizes, int n_in,
                              void* d_out, int out_size, void* d_ws, size_t ws_size,
                              hipStream_t stream) {
    const float* x_rgb   = (const float*)d_in[0];   // [4,3,64,64]
    const float* feature = (const float*)d_in[1];   // [4,64,64,64]
    float* out = (float*)d_out;                     // [4,3,64,64]

    size_t needK = (size_t)kB * kHW * kD * 2;              // 18.87 MB
    size_t needP = (size_t)kB * kHW * KSPLIT * 5 * 4;      // 1.31 MB
    if (ws_size >= needK + needP) {
        unsigned short* Kd = (unsigned short*)d_ws;
        float* partb = (float*)((char*)d_ws + needK);
        int total = kB * kHW * kD;
        nlwa_unfold<<<(total + 255) / 256, 256, 0, stream>>>(feature, Kd);
        nlwa_attn<<<kB * (kHW / QWG) * KSPLIT, 256, 0, stream>>>(Kd, x_rgb, partb);
        nlwa_merge<<<(kB * kHW + 255) / 256, 256, 0, stream>>>(partb, out);
    } else {
        nlwa_naive<<<dim3(kHW, kB), 64, 0, stream>>>(feature, x_rgb, out);
    }
}

// Round 4
// 120.970 us; speedup vs baseline: 2.6987x; 1.0322x over previous
//
#include <hip/hip_runtime.h>
#include <hip/hip_bf16.h>

typedef __attribute__((ext_vector_type(8))) short bf16x8;
typedef __attribute__((ext_vector_type(4))) float f32x4;

constexpr int kB = 4, kC = 64, kH = 64, kW = 64;
constexpr int kHW = kH * kW;      // 4096
constexpr int kD  = kC * 9;       // 576
constexpr int KSPLIT = 4;
constexpr int KBLK = 32;
constexpr int QWAVE = 64;         // q rows per wave (4 groups of 16)
constexpr int QWG = 256;          // 4 waves * 64 q
constexpr int NTILE = kHW / KSPLIT / KBLK;   // 32
constexpr int ROWB = kD * 2;      // 1152 bytes per LDS row

// Features pre-scaled by sqrt(10*log2e): S = mfma(K,Q) is directly in exp2 space.
#define FSCALE 3.79828370f

__device__ inline float bf16bits_to_f32(unsigned short u) {
    unsigned int w = ((unsigned int)u) << 16;
    return __builtin_bit_cast(float, w);
}

// ---------------- Phase 1: unfold + bf16 + pre-scale + T2 XOR pre-swizzle ----------------
// Element (b,v,d) stored at chunk (d>>3) ^ (v&7) within its row (16B chunks, 72/row).
__global__ __launch_bounds__(256)
void nlwa_unfold(const float* __restrict__ feat, unsigned short* __restrict__ Kd) {
    int idx = blockIdx.x * 256 + threadIdx.x;
    if (idx >= kB * kHW * kD) return;
    int d = idx % kD;
    int v = (idx / kD) % kHW;
    int b = idx / (kD * kHW);
    int c = d / 9, dl = d % 9;
    int y = (v >> 6) + dl / 3 - 1;
    int x = (v & 63) + dl % 3 - 1;
    float val = 0.f;
    if ((unsigned)y < 64u && (unsigned)x < 64u)
        val = feat[((b * kC + c) * kH + y) * kW + x] * FSCALE;
    int chunk = (d >> 3) ^ (v & 7);
    __hip_bfloat16 h = __float2bfloat16(val);
    Kd[(size_t)(b * kHW + v) * kD + (chunk << 3) + (d & 7)] = *(unsigned short*)&h;
}

// ---------------- Phase 2: flash attention, swapped mfma(K,Q), 64 q rows per wave ----------------
__global__ __launch_bounds__(256, 1)
void nlwa_attn(const unsigned short* __restrict__ Kd,
               const float* __restrict__ rgb,
               float* __restrict__ part) {
    __shared__ alignas(16) unsigned short Ks[2][KBLK][kD];   // 73,728 B

    // XCD-chunked swizzle: 256 wgs, 32 consecutive per XCD -> 2 (b,ks) K panels (~2.4MB) in its L2.
    int orig = blockIdx.x;
    int wg = (orig & 7) * 32 + (orig >> 3);
    int qblk = wg & 15;
    int pair = wg >> 4;
    int ks = pair & 3;
    int b  = pair >> 2;

    int tid = threadIdx.x, lane = tid & 63, wid = tid >> 6;
    int lr = lane & 15, lg = lane >> 4;
    int x7 = lr & 7;
    int qwave = qblk * QWG + wid * QWAVE;
    int k0 = ks * (kHW / KSPLIT);

    // ---- Q fragments to registers: 4 groups x 18 d-chunks (B-operand layout) ----
    bf16x8 qf[4][18];
    #pragma unroll
    for (int g = 0; g < 4; ++g) {
        int qrow = qwave + g * 16 + lr;
        const unsigned short* qbase = Kd + (size_t)(b * kHW + qrow) * kD;
        int s7 = qrow & 7;
        #pragma unroll
        for (int dc = 0; dc < 18; ++dc) {
            int chunk = (dc * 4 + lg) ^ s7;
            qf[g][dc] = *(const bf16x8*)(qbase + (chunk << 3));
        }
    }
    // Pin Q-frags in VGPRs: forbid spill-to-scratch / remat-from-global.
    #pragma unroll
    for (int g = 0; g < 4; ++g)
        #pragma unroll
        for (int dc = 0; dc < 18; ++dc)
            asm volatile("" : "+v"(qf[g][dc]));

    // ---- Seed online-softmax max with the self-logit  m = sum_d q_d^2 ----
    // (exact for any seed; self-logit is this q's diagonal S value up to rounding)
    float m[4], l[4] = {0.f, 0.f, 0.f, 0.f};
    float O[4][3] = {{0,0,0},{0,0,0},{0,0,0},{0,0,0}};
    #pragma unroll
    for (int g = 0; g < 4; ++g) {
        float ss = 0.f;
        #pragma unroll
        for (int dc = 0; dc < 18; ++dc)
            #pragma unroll
            for (int j = 0; j < 8; ++j) {
                float v = bf16bits_to_f32((unsigned short)qf[g][dc][j]);
                ss = fmaf(v, v, ss);
            }
        ss += __shfl_xor(ss, 16);
        ss += __shfl_xor(ss, 32);   // row self-logit (sum over all 4 lg quarters)
        m[g] = ss;
    }

    const unsigned short* ksrc = Kd + (size_t)(b * kHW + k0) * kD;
    unsigned short* lds0 = &Ks[0][0][0];

    auto stage = [&](int t, int buf) {
        const unsigned short* src = ksrc + (size_t)t * KBLK * kD;
        unsigned short* dstb = lds0 + (size_t)buf * KBLK * kD;
        #pragma unroll
        for (int it = 0; it < 9; ++it) {
            int base = it * 256 + wid * 64;   // wave-uniform chunk base
            __builtin_amdgcn_global_load_lds(
                (const __attribute__((address_space(1))) void*)(src + (size_t)(base + lane) * 8),
                (__attribute__((address_space(3))) void*)(dstb + (size_t)base * 8),
                16, 0, 0);
        }
    };

    stage(0, 0);
    __syncthreads();   // tile 0 resident

    // Per-lane swizzled base byte-offsets (tile-invariant): even/odd dc parity.
    // phys chunk = (dc*4+lg)^x7 ; odd-dc offset = even-dc offset XOR 64.
    int eoff = lr * ROWB + ((lg ^ x7) << 4);
    int ooff = lr * ROWB + (((lg ^ x7) ^ 4) << 4);

    int buf = 0;
    for (int t = 0; t < NTILE; ++t) {
        if (t + 1 < NTILE) stage(t + 1, buf ^ 1);   // prefetch next into other buffer

        const char* kb = (const char*)(lds0 + (size_t)buf * KBLK * kD);
        const char* bE = kb + eoff;
        const char* bO = kb + ooff;

        f32x4 acc[4][2];
        #pragma unroll
        for (int g = 0; g < 4; ++g)
            #pragma unroll
            for (int s = 0; s < 2; ++s)
                acc[g][s] = (f32x4){0.f, 0.f, 0.f, 0.f};

        #pragma unroll
        for (int dc = 0; dc < 18; ++dc) {
            const char* pb = (dc & 1) ? bO : bE;
            bf16x8 a0 = *(const bf16x8*)(pb + (dc >> 1) * 128);
            bf16x8 a1 = *(const bf16x8*)(pb + 16 * ROWB + (dc >> 1) * 128);
            acc[0][0] = __builtin_amdgcn_mfma_f32_16x16x32_bf16(a0, qf[0][dc], acc[0][0], 0, 0, 0);
            acc[1][0] = __builtin_amdgcn_mfma_f32_16x16x32_bf16(a0, qf[1][dc], acc[1][0], 0, 0, 0);
            acc[2][0] = __builtin_amdgcn_mfma_f32_16x16x32_bf16(a0, qf[2][dc], acc[2][0], 0, 0, 0);
            acc[3][0] = __builtin_amdgcn_mfma_f32_16x16x32_bf16(a0, qf[3][dc], acc[3][0], 0, 0, 0);
            acc[0][1] = __builtin_amdgcn_mfma_f32_16x16x32_bf16(a1, qf[0][dc], acc[0][1], 0, 0, 0);
            acc[1][1] = __builtin_amdgcn_mfma_f32_16x16x32_bf16(a1, qf[1][dc], acc[1][1], 0, 0, 0);
            acc[2][1] = __builtin_amdgcn_mfma_f32_16x16x32_bf16(a1, qf[2][dc], acc[2][1], 0, 0, 0);
            acc[3][1] = __builtin_amdgcn_mfma_f32_16x16x32_bf16(a1, qf[3][dc], acc[3][1], 0, 0, 0);
        }
        // acc[g][s][r] = S[k = k0 + t*32 + s*16 + lg*4 + r][q = qwave + g*16 + lr]

        float pm[4];
        #pragma unroll
        for (int g = 0; g < 4; ++g)
            pm[g] = fmaxf(
                fmaxf(fmaxf(acc[g][0][0], acc[g][0][1]), fmaxf(acc[g][0][2], acc[g][0][3])),
                fmaxf(fmaxf(acc[g][1][0], acc[g][1][1]), fmaxf(acc[g][1][2], acc[g][1][3])));

        float dmx = fmaxf(fmaxf(pm[0] - m[0], pm[1] - m[1]),
                          fmaxf(pm[2] - m[2], pm[3] - m[3]));
        if (__any(dmx >= -25.f)) {   // cheap wave-uniform liveness test
            int kt0 = k0 + t * KBLK;
            #pragma unroll
            for (int g = 0; g < 4; ++g) {
                float v = pm[g];
                v = fmaxf(v, __shfl_xor(v, 16));
                v = fmaxf(v, __shfl_xor(v, 32));          // per-q tile max (uniform over lg)
                float mn = fmaxf(m[g], v);
                float al = exp2f(m[g] - mn);
                m[g] = mn;
                l[g] *= al;
                O[g][0] *= al; O[g][1] *= al; O[g][2] *= al;
            }
            float4 rv[2][3];
            #pragma unroll
            for (int s = 0; s < 2; ++s)
                #pragma unroll
                for (int c = 0; c < 3; ++c)
                    rv[s][c] = *(const float4*)(rgb + (size_t)(b * 3 + c) * kHW + kt0 + s * 16 + lg * 4);
            #pragma unroll
            for (int g = 0; g < 4; ++g) {
                #pragma unroll
                for (int s = 0; s < 2; ++s) {
                    float p0 = exp2f(acc[g][s][0] - m[g]);
                    float p1 = exp2f(acc[g][s][1] - m[g]);
                    float p2 = exp2f(acc[g][s][2] - m[g]);
                    float p3 = exp2f(acc[g][s][3] - m[g]);
                    l[g] += p0 + p1 + p2 + p3;
                    #pragma unroll
                    for (int c = 0; c < 3; ++c)
                        O[g][c] += p0 * rv[s][c].x + p1 * rv[s][c].y
                                 + p2 * rv[s][c].z + p3 * rv[s][c].w;
                }
            }
        }
        __syncthreads();   // prefetch landed; all waves done with buf
        buf ^= 1;
    }

    // final cross-group (lg) reduction of per-lane partials
    #pragma unroll
    for (int g = 0; g < 4; ++g) {
        l[g] += __shfl_xor(l[g], 16); l[g] += __shfl_xor(l[g], 32);
        #pragma unroll
        for (int c = 0; c < 3; ++c) {
            O[g][c] += __shfl_xor(O[g][c], 16);
            O[g][c] += __shfl_xor(O[g][c], 32);
        }
    }
    if (lg == 0) {
        #pragma unroll
        for (int g = 0; g < 4; ++g) {
            int q = qwave + g * 16 + lr;
            float* p = part + ((size_t)(b * kHW + q) * KSPLIT + ks) * 5;
            p[0] = m[g]; p[1] = l[g]; p[2] = O[g][0]; p[3] = O[g][1]; p[4] = O[g][2];
        }
    }
}

// ---------------- Phase 3: merge the KSPLIT partials ----------------
__global__ __launch_bounds__(256)
void nlwa_merge(const float* __restrict__ part, float* __restrict__ out) {
    int idx = blockIdx.x * 256 + threadIdx.x;
    if (idx >= kB * kHW) return;
    int b = idx >> 12, q = idx & 4095;
    const float* p = part + (size_t)idx * KSPLIT * 5;
    float M = -INFINITY;
    #pragma unroll
    for (int s = 0; s < KSPLIT; ++s) M = fmaxf(M, p[s * 5]);
    float L = 0.f, o0 = 0.f, o1 = 0.f, o2 = 0.f;
    #pragma unroll
    for (int s = 0; s < KSPLIT; ++s) {
        float a = exp2f(p[s * 5] - M);
        L  += p[s * 5 + 1] * a;
        o0 += p[s * 5 + 2] * a;
        o1 += p[s * 5 + 3] * a;
        o2 += p[s * 5 + 4] * a;
    }
    float inv = 1.f / L;
    out[(b * 3 + 0) * kHW + q] = o0 * inv;
    out[(b * 3 + 1) * kHW + q] = o1 * inv;
    out[(b * 3 + 2) * kHW + q] = o2 * inv;
}

// ---------------- Fallback (ws too small): slow fp32, correct ----------------
__global__ __launch_bounds__(64)
void nlwa_naive(const float* __restrict__ feat, const float* __restrict__ rgb,
                float* __restrict__ out) {
    int p = blockIdx.x, b = blockIdx.y;
    int pi = p >> 6, pj = p & 63;
    int t = threadIdx.x;
    __shared__ float pdesc[kD];
    __shared__ float rows[kC][3][kW];
    __shared__ float red[64][5];

    for (int d = t; d < kD; d += 64) {
        int c = d / 9, dl = d % 9;
        int y = pi + dl / 3 - 1, x = pj + dl % 3 - 1;
        pdesc[d] = ((unsigned)y < 64u && (unsigned)x < 64u)
                 ? feat[((b * kC + c) * kH + y) * kW + x] : 0.f;
    }
    float m = -INFINITY, l = 0.f, O0 = 0.f, O1 = 0.f, O2 = 0.f;
    for (int qi = 0; qi < kH; ++qi) {
        __syncthreads();
        for (int f = t; f < kC * 3 * kW; f += 64) {
            int x = f & 63, yy = (f >> 6) % 3, c = f / (3 * kW);
            int y = qi + yy - 1;
            rows[c][yy][x] = ((unsigned)y < 64u) ? feat[((b * kC + c) * kH + y) * kW + x] : 0.f;
        }
        __syncthreads();
        float s = 0.f;
        for (int c = 0; c < kC; ++c)
            for (int dl = 0; dl < 9; ++dl) {
                int x = t + dl % 3 - 1;
                float fv = ((unsigned)x < 64u) ? rows[c][dl / 3][x] : 0.f;
                s += pdesc[c * 9 + dl] * fv;
            }
        s *= 14.4269504089f;
        int q = qi * 64 + t;
        float mn = fmaxf(m, s);
        float al = exp2f(m - mn);
        float pv = exp2f(s - mn);
        l = l * al + pv;
        O0 = O0 * al + pv * rgb[(b * 3 + 0) * kHW + q];
        O1 = O1 * al + pv * rgb[(b * 3 + 1) * kHW + q];
        O2 = O2 * al + pv * rgb[(b * 3 + 2) * kHW + q];
        m = mn;
    }
    red[t][0] = m; red[t][1] = l; red[t][2] = O0; red[t][3] = O1; red[t][4] = O2;
    __syncthreads();
    if (t == 0) {
        float M = -INFINITY;
        for (int i = 0; i < 64; ++i) M = fmaxf(M, red[i][0]);
        float L = 0, A = 0, Bv = 0, Cv = 0;
        for (int i = 0; i < 64; ++i) {
            float a = exp2f(red[i][0] - M);
            L += red[i][1] * a; A += red[i][2] * a; Bv += red[i][3] * a; Cv += red[i][4] * a;
        }
        out[(b * 3 + 0) * kHW + p] = A / L;
        out[(b * 3 + 1) * kHW + p] = Bv / L;
        out[(b * 3 + 2) * kHW + p] = Cv / L;
    }
}

extern "C" void kernel_launch(void* const* d_in, const int* in_sizes, int n_in,
                              void* d_out, int out_size, void* d_ws, size_t ws_size,
                              hipStream_t stream) {
    const float* x_rgb   = (const float*)d_in[0];   // [4,3,64,64]
    const float* feature = (const float*)d_in[1];   // [4,64,64,64]
    float* out = (float*)d_out;                     // [4,3,64,64]

    size_t needK = (size_t)kB * kHW * kD * 2;              // 18.87 MB
    size_t needP = (size_t)kB * kHW * KSPLIT * 5 * 4;      // 1.31 MB
    if (ws_size >= needK + needP) {
        unsigned short* Kd = (unsigned short*)d_ws;
        float* partb = (float*)((char*)d_ws + needK);
        int total = kB * kHW * kD;
        nlwa_unfold<<<(total + 255) / 256, 256, 0, stream>>>(feature, Kd);
        nlwa_attn<<<kB * (kHW / QWG) * KSPLIT, 256, 0, stream>>>(Kd, x_rgb, partb);
        nlwa_merge<<<(kB * kHW + 255) / 256, 256, 0, stream>>>(partb, out);
    } else {
        nlwa_naive<<<dim3(kHW, kB), 64, 0, stream>>>(feature, x_rgb, out);
    }
}

// Round 5
// 98.256 us; speedup vs baseline: 3.3226x; 1.2312x over previous
//
#include <hip/hip_runtime.h>
#include <hip/hip_bf16.h>

typedef __attribute__((ext_vector_type(8))) short bf16x8;
typedef __attribute__((ext_vector_type(4))) float f32x4;

constexpr int kB = 4, kC = 64, kH = 64, kW = 64;
constexpr int kHW = kH * kW;      // 4096
constexpr int kD  = kC * 9;       // 576
constexpr int KSPLIT = 4;
constexpr int KBLK = 32;
constexpr int QWAVE = 32;         // q rows per wave (2 groups of 16)
constexpr int QWG = 128;          // 4 waves * 32 q
constexpr int NTILE = kHW / KSPLIT / KBLK;   // 32
constexpr int ROWB = kD * 2;      // 1152 bytes per LDS row

// Features pre-scaled by sqrt(10*log2e): S = mfma(K,Q) is directly in exp2 space.
#define FSCALE 3.79828370f

__device__ inline float bf16bits_to_f32(unsigned short u) {
    unsigned int w = ((unsigned int)u) << 16;
    return __builtin_bit_cast(float, w);
}

// ---------------- Phase 1: unfold + bf16 + pre-scale + T2 XOR pre-swizzle ----------------
// Element (b,v,d) stored at chunk (d>>3) ^ (v&7) within its row (16B chunks, 72/row).
__global__ __launch_bounds__(256)
void nlwa_unfold(const float* __restrict__ feat, unsigned short* __restrict__ Kd) {
    int idx = blockIdx.x * 256 + threadIdx.x;
    if (idx >= kB * kHW * kD) return;
    int d = idx % kD;
    int v = (idx / kD) % kHW;
    int b = idx / (kD * kHW);
    int c = d / 9, dl = d % 9;
    int y = (v >> 6) + dl / 3 - 1;
    int x = (v & 63) + dl % 3 - 1;
    float val = 0.f;
    if ((unsigned)y < 64u && (unsigned)x < 64u)
        val = feat[((b * kC + c) * kH + y) * kW + x] * FSCALE;
    int chunk = (d >> 3) ^ (v & 7);
    __hip_bfloat16 h = __float2bfloat16(val);
    Kd[(size_t)(b * kHW + v) * kD + (chunk << 3) + (d & 7)] = *(unsigned short*)&h;
}

// ---------------- Phase 2: flash attention, swapped mfma(K,Q), 32 q rows per wave ----------------
// 2 waves/SIMD (two concurrent workgroups per CU) for latency hiding.
__global__ __launch_bounds__(256, 2)
void nlwa_attn(const unsigned short* __restrict__ Kd,
               const float* __restrict__ rgb,
               float* __restrict__ part) {
    __shared__ alignas(16) unsigned short Ks[2][KBLK][kD];   // 73,728 B (x2 wgs = 144KB/CU)

    // XCD-chunked swizzle: 512 wgs, 64 consecutive per XCD -> 2 (b,ks) K panels (~2.4MB) in its L2.
    int orig = blockIdx.x;
    int wg = (orig & 7) * 64 + (orig >> 3);
    int qblk = wg & 31;
    int pair = wg >> 5;
    int ks = pair & 3;
    int b  = pair >> 2;

    int tid = threadIdx.x, lane = tid & 63, wid = tid >> 6;
    int lr = lane & 15, lg = lane >> 4;
    int x7 = lr & 7;
    int qwave = qblk * QWG + wid * QWAVE;
    int k0 = ks * (kHW / KSPLIT);

    // ---- Q fragments to registers: 2 groups x 18 d-chunks (B-operand layout) ----
    bf16x8 qf[2][18];
    #pragma unroll
    for (int g = 0; g < 2; ++g) {
        int qrow = qwave + g * 16 + lr;
        const unsigned short* qbase = Kd + (size_t)(b * kHW + qrow) * kD;
        int s7 = qrow & 7;
        #pragma unroll
        for (int dc = 0; dc < 18; ++dc) {
            int chunk = (dc * 4 + lg) ^ s7;
            qf[g][dc] = *(const bf16x8*)(qbase + (chunk << 3));
        }
    }

    // ---- Seed online-softmax max with the self-logit  m = sum_d q_d^2 ----
    // (exact online softmax for any seed; self-logit is this q's diagonal S value)
    float m[2], l[2] = {0.f, 0.f};
    float O[2][3] = {{0,0,0},{0,0,0}};
    #pragma unroll
    for (int g = 0; g < 2; ++g) {
        float ss = 0.f;
        #pragma unroll
        for (int dc = 0; dc < 18; ++dc)
            #pragma unroll
            for (int j = 0; j < 8; ++j) {
                float v = bf16bits_to_f32((unsigned short)qf[g][dc][j]);
                ss = fmaf(v, v, ss);
            }
        ss += __shfl_xor(ss, 16);
        ss += __shfl_xor(ss, 32);   // row self-logit (sum over all 4 lg quarters)
        m[g] = ss;
    }

    const unsigned short* ksrc = Kd + (size_t)(b * kHW + k0) * kD;
    unsigned short* lds0 = &Ks[0][0][0];

    auto stage = [&](int t, int buf) {
        const unsigned short* src = ksrc + (size_t)t * KBLK * kD;
        unsigned short* dstb = lds0 + (size_t)buf * KBLK * kD;
        #pragma unroll
        for (int it = 0; it < 9; ++it) {
            int base = it * 256 + wid * 64;   // wave-uniform chunk base
            __builtin_amdgcn_global_load_lds(
                (const __attribute__((address_space(1))) void*)(src + (size_t)(base + lane) * 8),
                (__attribute__((address_space(3))) void*)(dstb + (size_t)base * 8),
                16, 0, 0);
        }
    };

    stage(0, 0);
    __syncthreads();   // tile 0 resident

    // Per-lane swizzled base byte-offsets (tile-invariant): even/odd dc parity.
    // phys chunk = (dc*4+lg)^x7 ; odd-dc offset = even-dc offset XOR 64.
    int eoff = lr * ROWB + ((lg ^ x7) << 4);
    int ooff = lr * ROWB + (((lg ^ x7) ^ 4) << 4);

    int buf = 0;
    for (int t = 0; t < NTILE; ++t) {
        if (t + 1 < NTILE) stage(t + 1, buf ^ 1);   // prefetch next into other buffer

        const char* kb = (const char*)(lds0 + (size_t)buf * KBLK * kD);
        const char* bE = kb + eoff;
        const char* bO = kb + ooff;

        f32x4 acc[2][2];
        #pragma unroll
        for (int g = 0; g < 2; ++g)
            #pragma unroll
            for (int s = 0; s < 2; ++s)
                acc[g][s] = (f32x4){0.f, 0.f, 0.f, 0.f};

        #pragma unroll
        for (int dc = 0; dc < 18; ++dc) {
            const char* pb = (dc & 1) ? bO : bE;
            bf16x8 a0 = *(const bf16x8*)(pb + (dc >> 1) * 128);
            bf16x8 a1 = *(const bf16x8*)(pb + 16 * ROWB + (dc >> 1) * 128);
            acc[0][0] = __builtin_amdgcn_mfma_f32_16x16x32_bf16(a0, qf[0][dc], acc[0][0], 0, 0, 0);
            acc[1][0] = __builtin_amdgcn_mfma_f32_16x16x32_bf16(a0, qf[1][dc], acc[1][0], 0, 0, 0);
            acc[0][1] = __builtin_amdgcn_mfma_f32_16x16x32_bf16(a1, qf[0][dc], acc[0][1], 0, 0, 0);
            acc[1][1] = __builtin_amdgcn_mfma_f32_16x16x32_bf16(a1, qf[1][dc], acc[1][1], 0, 0, 0);
        }
        // acc[g][s][r] = S[k = k0 + t*32 + s*16 + lg*4 + r][q = qwave + g*16 + lr]

        float pm[2];
        #pragma unroll
        for (int g = 0; g < 2; ++g)
            pm[g] = fmaxf(
                fmaxf(fmaxf(acc[g][0][0], acc[g][0][1]), fmaxf(acc[g][0][2], acc[g][0][3])),
                fmaxf(fmaxf(acc[g][1][0], acc[g][1][1]), fmaxf(acc[g][1][2], acc[g][1][3])));

        float dmx = fmaxf(pm[0] - m[0], pm[1] - m[1]);
        if (__any(dmx >= -25.f)) {   // cheap wave-uniform liveness test
            int kt0 = k0 + t * KBLK;
            #pragma unroll
            for (int g = 0; g < 2; ++g) {
                float v = pm[g];
                v = fmaxf(v, __shfl_xor(v, 16));
                v = fmaxf(v, __shfl_xor(v, 32));          // per-q tile max (uniform over lg)
                float mn = fmaxf(m[g], v);
                float al = exp2f(m[g] - mn);
                m[g] = mn;
                l[g] *= al;
                O[g][0] *= al; O[g][1] *= al; O[g][2] *= al;
            }
            float4 rv[2][3];
            #pragma unroll
            for (int s = 0; s < 2; ++s)
                #pragma unroll
                for (int c = 0; c < 3; ++c)
                    rv[s][c] = *(const float4*)(rgb + (size_t)(b * 3 + c) * kHW + kt0 + s * 16 + lg * 4);
            #pragma unroll
            for (int g = 0; g < 2; ++g) {
                #pragma unroll
                for (int s = 0; s < 2; ++s) {
                    float p0 = exp2f(acc[g][s][0] - m[g]);
                    float p1 = exp2f(acc[g][s][1] - m[g]);
                    float p2 = exp2f(acc[g][s][2] - m[g]);
                    float p3 = exp2f(acc[g][s][3] - m[g]);
                    l[g] += p0 + p1 + p2 + p3;
                    #pragma unroll
                    for (int c = 0; c < 3; ++c)
                        O[g][c] += p0 * rv[s][c].x + p1 * rv[s][c].y
                                 + p2 * rv[s][c].z + p3 * rv[s][c].w;
                }
            }
        }
        __syncthreads();   // prefetch landed; all waves done with buf
        buf ^= 1;
    }

    // final cross-group (lg) reduction of per-lane partials
    #pragma unroll
    for (int g = 0; g < 2; ++g) {
        l[g] += __shfl_xor(l[g], 16); l[g] += __shfl_xor(l[g], 32);
        #pragma unroll
        for (int c = 0; c < 3; ++c) {
            O[g][c] += __shfl_xor(O[g][c], 16);
            O[g][c] += __shfl_xor(O[g][c], 32);
        }
    }
    if (lg == 0) {
        #pragma unroll
        for (int g = 0; g < 2; ++g) {
            int q = qwave + g * 16 + lr;
            float* p = part + ((size_t)(b * kHW + q) * KSPLIT + ks) * 5;
            p[0] = m[g]; p[1] = l[g]; p[2] = O[g][0]; p[3] = O[g][1]; p[4] = O[g][2];
        }
    }
}

// ---------------- Phase 3: merge the KSPLIT partials ----------------
__global__ __launch_bounds__(256)
void nlwa_merge(const float* __restrict__ part, float* __restrict__ out) {
    int idx = blockIdx.x * 256 + threadIdx.x;
    if (idx >= kB * kHW) return;
    int b = idx >> 12, q = idx & 4095;
    const float* p = part + (size_t)idx * KSPLIT * 5;
    float M = -INFINITY;
    #pragma unroll
    for (int s = 0; s < KSPLIT; ++s) M = fmaxf(M, p[s * 5]);
    float L = 0.f, o0 = 0.f, o1 = 0.f, o2 = 0.f;
    #pragma unroll
    for (int s = 0; s < KSPLIT; ++s) {
        float a = exp2f(p[s * 5] - M);
        L  += p[s * 5 + 1] * a;
        o0 += p[s * 5 + 2] * a;
        o1 += p[s * 5 + 3] * a;
        o2 += p[s * 5 + 4] * a;
    }
    float inv = 1.f / L;
    out[(b * 3 + 0) * kHW + q] = o0 * inv;
    out[(b * 3 + 1) * kHW + q] = o1 * inv;
    out[(b * 3 + 2) * kHW + q] = o2 * inv;
}

// ---------------- Fallback (ws too small): slow fp32, correct ----------------
__global__ __launch_bounds__(64)
void nlwa_naive(const float* __restrict__ feat, const float* __restrict__ rgb,
                float* __restrict__ out) {
    int p = blockIdx.x, b = blockIdx.y;
    int pi = p >> 6, pj = p & 63;
    int t = threadIdx.x;
    __shared__ float pdesc[kD];
    __shared__ float rows[kC][3][kW];
    __shared__ float red[64][5];

    for (int d = t; d < kD; d += 64) {
        int c = d / 9, dl = d % 9;
        int y = pi + dl / 3 - 1, x = pj + dl % 3 - 1;
        pdesc[d] = ((unsigned)y < 64u && (unsigned)x < 64u)
                 ? feat[((b * kC + c) * kH + y) * kW + x] : 0.f;
    }
    float m = -INFINITY, l = 0.f, O0 = 0.f, O1 = 0.f, O2 = 0.f;
    for (int qi = 0; qi < kH; ++qi) {
        __syncthreads();
        for (int f = t; f < kC * 3 * kW; f += 64) {
            int x = f & 63, yy = (f >> 6) % 3, c = f / (3 * kW);
            int y = qi + yy - 1;
            rows[c][yy][x] = ((unsigned)y < 64u) ? feat[((b * kC + c) * kH + y) * kW + x] : 0.f;
        }
        __syncthreads();
        float s = 0.f;
        for (int c = 0; c < kC; ++c)
            for (int dl = 0; dl < 9; ++dl) {
                int x = t + dl % 3 - 1;
                float fv = ((unsigned)x < 64u) ? rows[c][dl / 3][x] : 0.f;
                s += pdesc[c * 9 + dl] * fv;
            }
        s *= 14.4269504089f;
        int q = qi * 64 + t;
        float mn = fmaxf(m, s);
        float al = exp2f(m - mn);
        float pv = exp2f(s - mn);
        l = l * al + pv;
        O0 = O0 * al + pv * rgb[(b * 3 + 0) * kHW + q];
        O1 = O1 * al + pv * rgb[(b * 3 + 1) * kHW + q];
        O2 = O2 * al + pv * rgb[(b * 3 + 2) * kHW + q];
        m = mn;
    }
    red[t][0] = m; red[t][1] = l; red[t][2] = O0; red[t][3] = O1; red[t][4] = O2;
    __syncthreads();
    if (t == 0) {
        float M = -INFINITY;
        for (int i = 0; i < 64; ++i) M = fmaxf(M, red[i][0]);
        float L = 0, A = 0, Bv = 0, Cv = 0;
        for (int i = 0; i < 64; ++i) {
            float a = exp2f(red[i][0] - M);
            L += red[i][1] * a; A += red[i][2] * a; Bv += red[i][3] * a; Cv += red[i][4] * a;
        }
        out[(b * 3 + 0) * kHW + p] = A / L;
        out[(b * 3 + 1) * kHW + p] = Bv / L;
        out[(b * 3 + 2) * kHW + p] = Cv / L;
    }
}

extern "C" void kernel_launch(void* const* d_in, const int* in_sizes, int n_in,
                              void* d_out, int out_size, void* d_ws, size_t ws_size,
                              hipStream_t stream) {
    const float* x_rgb   = (const float*)d_in[0];   // [4,3,64,64]
    const float* feature = (const float*)d_in[1];   // [4,64,64,64]
    float* out = (float*)d_out;                     // [4,3,64,64]

    size_t needK = (size_t)kB * kHW * kD * 2;              // 18.87 MB
    size_t needP = (size_t)kB * kHW * KSPLIT * 5 * 4;      // 1.31 MB
    if (ws_size >= needK + needP) {
        unsigned short* Kd = (unsigned short*)d_ws;
        float* partb = (float*)((char*)d_ws + needK);
        int total = kB * kHW * kD;
        nlwa_unfold<<<(total + 255) / 256, 256, 0, stream>>>(feature, Kd);
        nlwa_attn<<<kB * (kHW / QWG) * KSPLIT, 256, 0, stream>>>(Kd, x_rgb, partb);
        nlwa_merge<<<(kB * kHW + 255) / 256, 256, 0, stream>>>(partb, out);
    } else {
        nlwa_naive<<<dim3(kHW, kB), 64, 0, stream>>>(feature, x_rgb, out);
    }
}